// Round 1
// baseline (789.147 us; speedup 1.0000x reference)
//
#include <hip/hip_runtime.h>

#define K 11
#define TT 2048
#define START_TAG 10
#define STOP_TAG 9
#define L2E 1.4426950408889634f
#define LN2 0.6931471805599453f

// One sequence per 16-lane group (lane-in-group = CRF state, 11 active).
// Forward recursion kept in normal space (base-2): alpha_new[n] =
// 2^(feat[n]*log2e) * sum_p E2[n,p] * alpha[p], E2 = 2^(trans*log2e).
// exp2(-10000*log2e) == 0 handles the START/STOP constraint rows exactly.
// Renormalize by an exact power of two every 8 steps (ilogb/ldexp), track
// the exponent offset; worst-case 8-step growth < 2^113 so no overflow.
__global__ __launch_bounds__(256) void crf_nll_kernel(
    const float* __restrict__ feats,
    const int* __restrict__ tags,
    const float* __restrict__ trans,
    float* __restrict__ out,
    int nseq)
{
    __shared__ float trans_s[K * K];
    if (threadIdx.x < K * K) trans_s[threadIdx.x] = trans[threadIdx.x];
    __syncthreads();

    const int tid = blockIdx.x * blockDim.x + threadIdx.x;
    const int n = threadIdx.x & 15;          // state index within group
    const int seq = tid >> 4;
    if (seq >= nseq) return;

    const bool real = (n < K);
    const int nn = real ? n : 0;

    // Rotated transition row (mod-11) + precomputed bpermute source lanes.
    float erot[K];
    int srcl[K];
    const int wl = threadIdx.x & 63;
    const int gbase = wl & ~15;
#pragma unroll
    for (int r = 0; r < K; ++r) {
        int p = n + r; if (p >= K) p -= K;
        erot[r] = real ? exp2f(trans[n * K + p] * L2E) : 0.0f;
        srcl[r] = gbase + (real ? p : 0);
    }
    const float pstop = real ? exp2f(trans[STOP_TAG * K + n] * L2E) : 0.0f;

    const float* fb = feats + (size_t)seq * TT * K;
    const int* tb = tags + (size_t)seq * TT;

    float a = (n == START_TAG) ? 1.0f : 0.0f;   // alpha (normal space)
    int cacc = 0;                               // accumulated log2 offset
    float goldt = 0.0f, goldf = 0.0f;
    int prev = START_TAG;

    float fA[8], fB[8];
    int tgA[8], tgB[8];

    auto prefetch = [&](float (&fR)[8], int (&tR)[8], int t0) {
        const float* fp = fb + (size_t)t0 * K;
#pragma unroll
        for (int j = 0; j < 8; ++j) fR[j] = fp[j * K + nn];
        int4 u0 = *(const int4*)(tb + t0);
        int4 u1 = *(const int4*)(tb + t0 + 4);
        tR[0] = u0.x; tR[1] = u0.y; tR[2] = u0.z; tR[3] = u0.w;
        tR[4] = u1.x; tR[5] = u1.y; tR[6] = u1.z; tR[7] = u1.w;
    };

    auto step8 = [&](float (&fR)[8], int (&tR)[8]) {
#pragma unroll
        for (int j = 0; j < 8; ++j) {
            float av = a;
            float acc0 = erot[0] * av;
            float acc1 = erot[1] * __shfl(av, srcl[1]);
            float acc2 = erot[2] * __shfl(av, srcl[2]);
            float acc3 = erot[3] * __shfl(av, srcl[3]);
            acc0 += erot[4] * __shfl(av, srcl[4]);
            acc1 += erot[5] * __shfl(av, srcl[5]);
            acc2 += erot[6] * __shfl(av, srcl[6]);
            acc3 += erot[7] * __shfl(av, srcl[7]);
            acc0 += erot[8] * __shfl(av, srcl[8]);
            acc1 += erot[9] * __shfl(av, srcl[9]);
            acc2 += erot[10] * __shfl(av, srcl[10]);
            float S = (acc0 + acc1) + (acc2 + acc3);
            float f = fR[j];
            a = S * exp2f(f * L2E);
            // gold score, folded in (feat value already in lane tg's reg f)
            int tg = tR[j];
            goldf += (n == tg) ? f : 0.0f;
            goldt += trans_s[tg * K + prev];
            prev = tg;
        }
        // exact power-of-two renormalization
        float mx = a;
        mx = fmaxf(mx, __shfl_xor(mx, 1));
        mx = fmaxf(mx, __shfl_xor(mx, 2));
        mx = fmaxf(mx, __shfl_xor(mx, 4));
        mx = fmaxf(mx, __shfl_xor(mx, 8));
        int ex = ilogbf(mx);
        a = ldexpf(a, -ex);
        cacc += ex;
    };

    prefetch(fA, tgA, 0);
    for (int blk = 0; blk < TT / 8; blk += 2) {
        int t1 = (blk + 1) * 8; if (t1 > TT - 8) t1 = TT - 8;
        prefetch(fB, tgB, t1);
        step8(fA, tgA);
        int t2 = (blk + 2) * 8; if (t2 > TT - 8) t2 = TT - 8;
        prefetch(fA, tgA, t2);
        step8(fB, tgB);
    }

    // forward score: ln( sum_n alpha_n * 2^G2stop_n ) + cacc*ln2
    float w = a * pstop;
    w += __shfl_xor(w, 1);
    w += __shfl_xor(w, 2);
    w += __shfl_xor(w, 4);
    w += __shfl_xor(w, 8);
    float fs = (log2f(w) + (float)cacc) * LN2;

    goldf += __shfl_xor(goldf, 1);
    goldf += __shfl_xor(goldf, 2);
    goldf += __shfl_xor(goldf, 4);
    goldf += __shfl_xor(goldf, 8);

    float gold = goldt + goldf + trans_s[STOP_TAG * K + prev];
    if (n == 0) out[seq] = fs - gold;
}

extern "C" void kernel_launch(void* const* d_in, const int* in_sizes, int n_in,
                              void* d_out, int out_size, void* d_ws, size_t ws_size,
                              hipStream_t stream) {
    const float* feats = (const float*)d_in[0];
    const int* tags = (const int*)d_in[1];
    const float* trans = (const float*)d_in[2];
    float* out = (float*)d_out;
    const int nseq = in_sizes[1] / TT;                 // 4096
    const int threads = 256;
    const int blocks = (nseq * 16 + threads - 1) / threads;   // 256
    hipLaunchKernelGGL(crf_nll_kernel, dim3(blocks), dim3(threads), 0, stream,
                       feats, tags, trans, out, nseq);
}

// Round 2
// 703.849 us; speedup vs baseline: 1.1212x; 1.1212x over previous
//
#include <hip/hip_runtime.h>

#define K 11
#define TT 2048
#define START_TAG 10
#define STOP_TAG 9
#define L2E 1.4426950408889634f
#define LN2 0.6931471805599453f

// DPP row-rotate-right by S within 16-lane rows (VALU-latency cross-lane).
template<int S>
__device__ __forceinline__ float ror16(float x) {
    return __int_as_float(__builtin_amdgcn_update_dpp(
        __float_as_int(x), __float_as_int(x), 0x120 + S, 0xF, 0xF, false));
}

// One sequence per 16-lane group. Replication invariant: lane l holds
// alpha[l mod 11] (lanes 11..15 mirror states 0..4 and update with that
// state's rule, so the invariant is inductive). The mod-11 gather
// a[(st+r) mod 11] is served by DPP row_ror s with s = r (valid n+r<=15)
// or s = r+5 (valid n+r>=16: wrap -16 then replication -11 net +(r) mod 11).
// Choice folded into per-lane coefficients w[s]: S = sum_s w[s]*ror_s(a).
// Forward recursion in normal space base-2; exact pow2 renorm every 8 steps.
__global__ __launch_bounds__(256, 1) void crf_nll_kernel(
    const float* __restrict__ feats,
    const int* __restrict__ tags,
    const float* __restrict__ trans,
    float* __restrict__ out,
    int nseq)
{
    __shared__ float trans_s[K * K];
    if (threadIdx.x < K * K) trans_s[threadIdx.x] = trans[threadIdx.x];
    __syncthreads();

    const int tid = blockIdx.x * blockDim.x + threadIdx.x;
    const int n = threadIdx.x & 15;              // lane within group
    const int seq = tid >> 4;
    if (seq >= nseq) return;

    const int st = (n < K) ? n : n - K;          // this lane's state (mod 11)

    // Per-lane rotation coefficients. w[s] multiplies ror16<s>(a); w[0] is own.
    float w[16];
#pragma unroll
    for (int s = 0; s < 16; ++s) w[s] = 0.0f;
#pragma unroll
    for (int r = 0; r < K; ++r) {
        int p = st + r; if (p >= K) p -= K;      // prev state delivered
        float e = exp2f(trans[st * K + p] * L2E); // 0 for NEG rows/cols
        int s = (r == 0) ? 0 : ((n + r <= 15) ? r : r + 5);
        w[s] = e;
    }
    const float pstop = (n < K) ? exp2f(trans[STOP_TAG * K + st] * L2E) : 0.0f;

    const float* fb = feats + (size_t)seq * TT * K;
    const int* tb = tags + (size_t)seq * TT;

    float a = (n == START_TAG) ? 1.0f : 0.0f;    // alpha (normal space)
    int cacc = 0;                                // accumulated log2 offset
    float goldt = 0.0f, goldf = 0.0f;
    int prev = START_TAG;

    float fA[16], fB[16];
    int gA[16], gB[16];

    auto prefetch = [&](float (&fR)[16], int (&gR)[16], int t0) {
        const float* fp = fb + (size_t)t0 * K + st;
#pragma unroll
        for (int j = 0; j < 16; ++j) fR[j] = fp[j * K];
        const int4* tp = (const int4*)(tb + t0);
#pragma unroll
        for (int q = 0; q < 4; ++q) {
            int4 u = tp[q];
            gR[4 * q + 0] = u.x; gR[4 * q + 1] = u.y;
            gR[4 * q + 2] = u.z; gR[4 * q + 3] = u.w;
        }
    };

    auto step16 = [&](float (&fR)[16], int (&gR)[16]) {
#pragma unroll
        for (int j = 0; j < 16; ++j) {
            float av = a;
            float acc0 = w[0] * av;
            float acc1 = w[1] * ror16<1>(av);
            float acc2 = w[2] * ror16<2>(av);
            float acc3 = w[3] * ror16<3>(av);
            acc0 = fmaf(w[4],  ror16<4>(av),  acc0);
            acc1 = fmaf(w[5],  ror16<5>(av),  acc1);
            acc2 = fmaf(w[6],  ror16<6>(av),  acc2);
            acc3 = fmaf(w[7],  ror16<7>(av),  acc3);
            acc0 = fmaf(w[8],  ror16<8>(av),  acc0);
            acc1 = fmaf(w[9],  ror16<9>(av),  acc1);
            acc2 = fmaf(w[10], ror16<10>(av), acc2);
            acc3 = fmaf(w[11], ror16<11>(av), acc3);
            acc0 = fmaf(w[12], ror16<12>(av), acc0);
            acc1 = fmaf(w[13], ror16<13>(av), acc1);
            acc2 = fmaf(w[14], ror16<14>(av), acc2);
            acc3 = fmaf(w[15], ror16<15>(av), acc3);
            float S = (acc0 + acc1) + (acc2 + acc3);
            // exp2 depends only on prefetched feat -> schedules off-chain
            a = S * exp2f(fR[j] * L2E);

            int tg = gR[j];
            goldf += (n == tg) ? fR[j] : 0.0f;
            goldt += trans_s[tg * K + prev];
            prev = tg;

            if ((j & 7) == 7) {  // exact pow2 renorm, every 8 steps
                float m = a;
                m = fmaxf(m, ror16<1>(m));
                m = fmaxf(m, ror16<2>(m));
                m = fmaxf(m, ror16<4>(m));
                m = fmaxf(m, ror16<8>(m));
                int ex = ((__float_as_int(m) >> 23) & 0xFF) - 127;
                a *= __int_as_float((127 - ex) << 23);   // exact *2^-ex
                cacc += ex;
            }
        }
    };

    prefetch(fA, gA, 0);
#pragma unroll 1
    for (int b = 0; b < TT / 16; b += 2) {
        prefetch(fB, gB, (b + 1) * 16);
        step16(fA, gA);
        int tn = (b + 2 < TT / 16) ? (b + 2) * 16 : (TT - 16);
        prefetch(fA, gA, tn);   // last iter re-reads tail, unused
        step16(fB, gB);
    }

    // forward score: ln( sum_states a*pstop ) + cacc*ln2 (replicas carry 0)
    float wv = a * pstop;
    wv += ror16<1>(wv);
    wv += ror16<2>(wv);
    wv += ror16<4>(wv);
    wv += ror16<8>(wv);
    float fs = (log2f(wv) + (float)cacc) * LN2;

    goldf += ror16<1>(goldf);
    goldf += ror16<2>(goldf);
    goldf += ror16<4>(goldf);
    goldf += ror16<8>(goldf);

    float gold = goldt + goldf + trans_s[STOP_TAG * K + prev];
    if (n == 0) out[seq] = fs - gold;
}

extern "C" void kernel_launch(void* const* d_in, const int* in_sizes, int n_in,
                              void* d_out, int out_size, void* d_ws, size_t ws_size,
                              hipStream_t stream) {
    const float* feats = (const float*)d_in[0];
    const int* tags = (const int*)d_in[1];
    const float* trans = (const float*)d_in[2];
    float* out = (float*)d_out;
    const int nseq = in_sizes[1] / TT;                        // 4096
    const int threads = 256;
    const int blocks = (nseq * 16 + threads - 1) / threads;   // 256
    hipLaunchKernelGGL(crf_nll_kernel, dim3(blocks), dim3(threads), 0, stream,
                       feats, tags, trans, out, nseq);
}

// Round 3
// 671.963 us; speedup vs baseline: 1.1744x; 1.0475x over previous
//
#include <hip/hip_runtime.h>

#define K 11
#define TT 2048
#define NB (TT / 16)
#define START_TAG 10
#define STOP_TAG 9
#define L2E 1.4426950408889634f
#define LN2 0.6931471805599453f

// DPP row-rotate-right by S within 16-lane rows (VALU-latency cross-lane).
template<int S>
__device__ __forceinline__ float ror16(float x) {
    return __int_as_float(__builtin_amdgcn_update_dpp(
        __float_as_int(x), __float_as_int(x), 0x120 + S, 0xF, 0xF, false));
}

// One sequence per 16-lane group. Lane l holds alpha[l mod 11] (lanes 11..15
// mirror states 0..4; inductive). Mod-11 gather served by DPP row_ror s with
// s = r (n+r<=15) or s = r+5 (wrap), folded into per-lane coefficients w[s].
// Forward recursion in normal space base-2; exact pow2 renorm every 8 steps.
// Per 16-step block: phase0 issue LDS gold reads -> phase1 hoisted v_exp_f32
// (hides LDS latency) -> phase2 pure-VALU serial chain -> phase3 gold sums.
__global__ __launch_bounds__(256, 1) void crf_nll_kernel(
    const float* __restrict__ feats,
    const int* __restrict__ tags,
    const float* __restrict__ trans,
    float* __restrict__ out,
    int nseq)
{
    __shared__ float T2[K * 16];   // padded gold table: T2[tg*16+prev]
    if (threadIdx.x < K * 16) {
        int r = threadIdx.x >> 4, c = threadIdx.x & 15;
        T2[threadIdx.x] = (c < K) ? trans[r * K + c] : 0.0f;
    }
    __syncthreads();

    const int tid = blockIdx.x * blockDim.x + threadIdx.x;
    const int n = threadIdx.x & 15;
    const int seq = tid >> 4;
    if (seq >= nseq) return;
    const int st = (n < K) ? n : n - K;

    float w[16];
#pragma unroll
    for (int s = 0; s < 16; ++s) w[s] = 0.0f;
#pragma unroll
    for (int r = 0; r < K; ++r) {
        int p = st + r; if (p >= K) p -= K;
        float e = __builtin_amdgcn_exp2f(trans[st * K + p] * L2E);
        int s = (r == 0) ? 0 : ((n + r <= 15) ? r : r + 5);
        w[s] = e;
    }
    const float pstop =
        (n < K) ? __builtin_amdgcn_exp2f(trans[STOP_TAG * K + st] * L2E) : 0.0f;

    const float* fb = feats + (size_t)seq * TT * K;
    const int* tb = tags + (size_t)seq * TT;

    float a = (n == START_TAG) ? 1.0f : 0.0f;
    int cacc = 0;
    float goldt = 0.0f, goldf = 0.0f;
    int prev = START_TAG;

    float fA[16], fB[16];
    int gA[16], gB[16];

    auto prefetch = [&](float (&f)[16], int (&g)[16], int blk) {
        const float* fp = fb + (size_t)blk * 16 * K + st;
#pragma unroll
        for (int j = 0; j < 16; ++j) f[j] = fp[j * K];
        const int4* tp = (const int4*)(tb + blk * 16);
#pragma unroll
        for (int q = 0; q < 4; ++q) {
            int4 u = tp[q];
            g[4 * q + 0] = u.x; g[4 * q + 1] = u.y;
            g[4 * q + 2] = u.z; g[4 * q + 3] = u.w;
        }
    };

    auto process = [&](float (&f)[16], int (&g)[16]) {
        // phase 0: issue all gold-transition LDS reads (addresses off-chain)
        float tv[16];
        {
            int pv = prev;
#pragma unroll
            for (int j = 0; j < 16; ++j) {
                tv[j] = T2[(g[j] << 4) + pv];
                pv = g[j];
            }
        }
        // phase 1: hoisted transcendentals (hide LDS latency behind v_exp issue)
        float e[16];
#pragma unroll
        for (int j = 0; j < 16; ++j)
            e[j] = __builtin_amdgcn_exp2f(f[j] * L2E);
        // phase 2: pure-VALU serial chain
#pragma unroll
        for (int j = 0; j < 16; ++j) {
            float av = a;
            float acc0 = w[0] * av;
            float acc1 = w[1] * ror16<1>(av);
            float acc2 = w[2] * ror16<2>(av);
            float acc3 = w[3] * ror16<3>(av);
            acc0 = fmaf(w[4],  ror16<4>(av),  acc0);
            acc1 = fmaf(w[5],  ror16<5>(av),  acc1);
            acc2 = fmaf(w[6],  ror16<6>(av),  acc2);
            acc3 = fmaf(w[7],  ror16<7>(av),  acc3);
            acc0 = fmaf(w[8],  ror16<8>(av),  acc0);
            acc1 = fmaf(w[9],  ror16<9>(av),  acc1);
            acc2 = fmaf(w[10], ror16<10>(av), acc2);
            acc3 = fmaf(w[11], ror16<11>(av), acc3);
            acc0 = fmaf(w[12], ror16<12>(av), acc0);
            acc1 = fmaf(w[13], ror16<13>(av), acc1);
            acc2 = fmaf(w[14], ror16<14>(av), acc2);
            acc3 = fmaf(w[15], ror16<15>(av), acc3);
            float S = (acc0 + acc1) + (acc2 + acc3);
            a = S * e[j];
            if ((j & 7) == 7) {  // exact pow2 renorm
                float m = a;
                m = fmaxf(m, ror16<1>(m));
                m = fmaxf(m, ror16<2>(m));
                m = fmaxf(m, ror16<4>(m));
                m = fmaxf(m, ror16<8>(m));
                int ex = ((__float_as_int(m) >> 23) & 0xFF) - 127;
                a *= __int_as_float((127 - ex) << 23);   // exact *2^-ex
                cacc += ex;
            }
        }
        // phase 3: gold sums (single lgkm drain, covered by phases 1-2)
        float gt = 0.0f, gf = 0.0f;
#pragma unroll
        for (int j = 0; j < 16; ++j) {
            gt += tv[j];
            gf += (n == g[j]) ? f[j] : 0.0f;
        }
        goldt += gt;
        goldf += gf;
        prev = g[15];
    };

    prefetch(fA, gA, 0);
#pragma unroll 1
    for (int b = 0; b < NB; b += 2) {
        int b1 = (b + 1 < NB) ? b + 1 : NB - 1;
        prefetch(fB, gB, b1);
        process(fA, gA);
        int b2 = (b + 2 < NB) ? b + 2 : NB - 1;
        prefetch(fA, gA, b2);   // tail re-read, unused
        process(fB, gB);
    }

    // forward score: ln( sum_states a*pstop ) + cacc*ln2 (replicas carry 0)
    float wv = a * pstop;
    wv += ror16<1>(wv);
    wv += ror16<2>(wv);
    wv += ror16<4>(wv);
    wv += ror16<8>(wv);
    float fs = (__builtin_amdgcn_logf(wv) + (float)cacc) * LN2;

    goldf += ror16<1>(goldf);
    goldf += ror16<2>(goldf);
    goldf += ror16<4>(goldf);
    goldf += ror16<8>(goldf);

    float gold = goldt + goldf + T2[STOP_TAG * 16 + prev];
    if (n == 0) out[seq] = fs - gold;
}

extern "C" void kernel_launch(void* const* d_in, const int* in_sizes, int n_in,
                              void* d_out, int out_size, void* d_ws, size_t ws_size,
                              hipStream_t stream) {
    const float* feats = (const float*)d_in[0];
    const int* tags = (const int*)d_in[1];
    const float* trans = (const float*)d_in[2];
    float* out = (float*)d_out;
    const int nseq = in_sizes[1] / TT;                        // 4096
    const int threads = 256;
    const int blocks = (nseq * 16 + threads - 1) / threads;   // 256
    hipLaunchKernelGGL(crf_nll_kernel, dim3(blocks), dim3(threads), 0, stream,
                       feats, tags, trans, out, nseq);
}